// Round 10
// baseline (168.472 us; speedup 1.0000x reference)
//
#include <hip/hip_runtime.h>

#define BB 2
#define SS 2048
#define DD 1024
#define NH 16
#define NKVH 4
#define HD 64
#define QKVN 1536          // fused Wqkv output columns: 1024 q | 256 k | 256 v
#define SCALE 0.125f       // 64^-0.5, exact power of 2 -> folded into Q frags

typedef __bf16 bf16;
typedef __bf16 bf16x4 __attribute__((ext_vector_type(4)));
typedef __bf16 bf16x8 __attribute__((ext_vector_type(8)));
typedef float floatx4 __attribute__((ext_vector_type(4)));
typedef short short4s __attribute__((ext_vector_type(4)));

#define ASYNC16(gp, lp) __builtin_amdgcn_global_load_lds(                      \
    (const __attribute__((address_space(1))) unsigned int*)(gp),               \
    (__attribute__((address_space(3))) unsigned int*)(lp), 16, 0, 0)

// hardware 2^x (v_exp_f32 is natively base-2)
static __device__ __forceinline__ float exp2_hw(float x) {
#if __has_builtin(__builtin_amdgcn_exp2f)
    return __builtin_amdgcn_exp2f(x);
#else
    float r; asm("v_exp_f32 %0, %1" : "=v"(r) : "v"(x)); return r;
#endif
}

static __device__ __forceinline__ float max3f(float a, float b, float c) {
    return fmaxf(fmaxf(a, b), c);
}

// K=16 bf16 MFMA: A-frag layout (row=lane&15, k=quad*4+e) == our S^T C-layout,
// so P feeds PV with ZERO transpose (no p_lds roundtrip).
static __device__ __forceinline__ floatx4 mfma16(bf16x4 a, bf16x4 b, floatx4 c) {
#if __has_builtin(__builtin_amdgcn_mfma_f32_16x16x16bf16_1k)
    return __builtin_amdgcn_mfma_f32_16x16x16bf16_1k(
        __builtin_bit_cast(short4s, a), __builtin_bit_cast(short4s, b), c, 0, 0, 0);
#else
    asm("v_mfma_f32_16x16x16_bf16 %0, %1, %2, %0" : "+v"(c) : "v"(a), "v"(b));
    return c;
#endif
}

// ---------- prep: LDS-tiled weight transposes + hs cast ----------
__global__ __launch_bounds__(256) void prep_kernel(const float* __restrict__ hs,
                                                   const float* __restrict__ Wq,
                                                   const float* __restrict__ Wk,
                                                   const float* __restrict__ Wv,
                                                   const float* __restrict__ Wo,
                                                   bf16* __restrict__ hsb,
                                                   bf16* __restrict__ WqkvT,
                                                   bf16* __restrict__ WoT) {
    __shared__ bf16 tl[64 * 66];
    int bidx = blockIdx.x, t = threadIdx.x;
    const int NT_QKV = 16 * 24;    // K/64 x QKVN/64
    const int NT_WO  = 16 * 16;
    if (bidx < NT_QKV + NT_WO) {
        int k0, n0, stride;
        const float* src;
        bf16* dst;
        if (bidx < NT_QKV) {
            int tk = bidx / 24, tn = bidx - tk * 24;
            k0 = tk * 64; n0 = tn * 64;
            if (n0 < 1024)      { src = Wq + n0;          stride = 1024; }
            else if (n0 < 1280) { src = Wk + (n0 - 1024); stride = 256;  }
            else                { src = Wv + (n0 - 1280); stride = 256;  }
            dst = WqkvT + (size_t)n0 * DD + k0;
        } else {
            int j = bidx - NT_QKV;
            int tk = j >> 4, tn = j & 15;
            k0 = tk * 64; n0 = tn * 64;
            src = Wo + n0; stride = 1024;
            dst = WoT + (size_t)n0 * DD + k0;
        }
        int c = t & 63, r0 = (t >> 6) * 16;
        for (int j = 0; j < 16; ++j)
            tl[c * 66 + r0 + j] = (bf16)src[(size_t)(k0 + r0 + j) * stride + c];
        __syncthreads();
        for (int j = 0; j < 16; ++j)
            dst[(size_t)(r0 + j) * DD + c] = tl[(r0 + j) * 66 + c];
    } else {
        int i = (bidx - (NT_QKV + NT_WO)) * 256 + t;   // n4 = 1048576 exactly
        float4 v = ((const float4*)hs)[i];
        ((bf16x4*)hsb)[i] = bf16x4{(bf16)v.x, (bf16)v.y, (bf16)v.z, (bf16)v.w};
    }
}

// ---------- QKV GEMM (128x64 tile, BK=128, swizzled LDS) + RoPE epilogue -----
// R7 measured-best config (163.9 us total). Grid 768 = 3/CU.
__global__ __launch_bounds__(256) void gemm_qkv(const bf16* __restrict__ A,
                                                const bf16* __restrict__ Bt,
                                                const float* __restrict__ cosb,
                                                const float* __restrict__ sinb,
                                                bf16* __restrict__ Qr,
                                                bf16* __restrict__ Kr,
                                                bf16* __restrict__ Vt) {
    __shared__ __align__(16) bf16 As[128 * 128];   // 32 KB
    __shared__ __align__(16) bf16 Bs[64 * 128];    // 16 KB
    int t = threadIdx.x;
    int wave = t >> 6, lane = t & 63;
    int lm = lane & 15, quad = lane >> 4;
    int m0 = blockIdx.x * 128, n0 = blockIdx.y * 64;
    int wr = wave >> 1, wc = wave & 1;      // 64m x 32n per wave
    const int K = DD;

    int srow = t >> 4;                      // 0..15
    int sblk = (t & 15) ^ (srow & 7);       // pre-swizzled 8-elem col block
    const bf16* ga = A  + (size_t)(m0 + srow) * K + sblk * 8;
    const bf16* gb = Bt + (size_t)(n0 + srow) * K + sblk * 8;

    floatx4 acc[4][2];
    for (int i = 0; i < 4; ++i)
        for (int j = 0; j < 2; ++j) acc[i][j] = floatx4{0.f, 0.f, 0.f, 0.f};

    int lm7 = lm & 7;
    for (int ks = 0; ks < K; ks += 128) {
        __syncthreads();
        ASYNC16(ga + ks,                  &As[0 * 2048 + wave * 512]);
        ASYNC16(ga + ks + (size_t)16*K,   &As[1 * 2048 + wave * 512]);
        ASYNC16(ga + ks + (size_t)32*K,   &As[2 * 2048 + wave * 512]);
        ASYNC16(ga + ks + (size_t)48*K,   &As[3 * 2048 + wave * 512]);
        ASYNC16(ga + ks + (size_t)64*K,   &As[4 * 2048 + wave * 512]);
        ASYNC16(ga + ks + (size_t)80*K,   &As[5 * 2048 + wave * 512]);
        ASYNC16(ga + ks + (size_t)96*K,   &As[6 * 2048 + wave * 512]);
        ASYNC16(ga + ks + (size_t)112*K,  &As[7 * 2048 + wave * 512]);
        ASYNC16(gb + ks,                  &Bs[0 * 2048 + wave * 512]);
        ASYNC16(gb + ks + (size_t)16*K,   &Bs[1 * 2048 + wave * 512]);
        ASYNC16(gb + ks + (size_t)32*K,   &Bs[2 * 2048 + wave * 512]);
        ASYNC16(gb + ks + (size_t)48*K,   &Bs[3 * 2048 + wave * 512]);
        __syncthreads();
        for (int kh = 0; kh < 4; ++kh) {
            bf16x8 af[4], bfr[2];
            int blk = (kh * 4 + quad) ^ lm7;
            for (int mi = 0; mi < 4; ++mi)
                af[mi] = *(const bf16x8*)&As[(wr * 64 + mi * 16 + lm) * 128 + blk * 8];
            for (int ni = 0; ni < 2; ++ni)
                bfr[ni] = *(const bf16x8*)&Bs[(wc * 32 + ni * 16 + lm) * 128 + blk * 8];
            for (int mi = 0; mi < 4; ++mi)
                for (int ni = 0; ni < 2; ++ni)
                    acc[mi][ni] = __builtin_amdgcn_mfma_f32_16x16x32_bf16(
                        af[mi], bfr[ni], acc[mi][ni], 0, 0, 0);
        }
    }
    bool odd = lm & 1;
    for (int mi = 0; mi < 4; ++mi)
        for (int ni = 0; ni < 2; ++ni) {
            int c0 = n0 + wc * 32 + ni * 16;
            int row0 = m0 + wr * 64 + mi * 16 + quad * 4;
            floatx4 a = acc[mi][ni];
            int d = (c0 & 63) + lm;
            if (c0 < 1280) {               // Q or K: apply RoPE
                int ii = d >> 1;
                for (int r = 0; r < 4; ++r) {
                    int row = row0 + r;
                    float self = a[r];
                    float part = __shfl_xor(self, 1);
                    float cc = cosb[(size_t)row * 32 + ii];
                    float sn = sinb[(size_t)row * 32 + ii];
                    float outv = odd ? fmaf(part, sn, self * cc)
                                     : fmaf(self, cc, -part * sn);
                    int s = row & (SS - 1), b = row >> 11;
                    if (c0 < 1024) {
                        int h = c0 >> 6;
                        Qr[((size_t)(b * NH + h) * SS + s) * HD + d] = (bf16)outv;
                    } else {
                        int kvh = (c0 - 1024) >> 6;
                        Kr[((size_t)(b * NKVH + kvh) * SS + s) * HD + d] = (bf16)outv;
                    }
                }
            } else {                       // V: transposed packed store
                int kvh = (c0 - 1280) >> 6;
                bf16x4 pk = {(bf16)a[0], (bf16)a[1], (bf16)a[2], (bf16)a[3]};
                int s0 = row0 & (SS - 1), b = row0 >> 11;
                *(bf16x4*)&Vt[((size_t)(b * NKVH + kvh) * HD + d) * SS + s0] = pk;
            }
        }
}

// ---------- O-projection GEMM (128x64 tile, BK=128, swizzled, fp32 out) -----
// R7 measured-best config (R9's 64x64 @4/CU lost 4.4us: tile too small,
// 2x B staging + half MFMA-per-barrier).
__global__ __launch_bounds__(256) void gemm_out(const bf16* __restrict__ A,
                                                const bf16* __restrict__ Bt,
                                                float* __restrict__ Cf,
                                                int M, int N, int K) {
    __shared__ __align__(16) bf16 As[128 * 128];
    __shared__ __align__(16) bf16 Bs[64 * 128];
    int t = threadIdx.x;
    int wave = t >> 6, lane = t & 63;
    int lm = lane & 15, quad = lane >> 4;
    int m0 = blockIdx.x * 128, n0 = blockIdx.y * 64;
    int wr = wave >> 1, wc = wave & 1;

    int srow = t >> 4;
    int sblk = (t & 15) ^ (srow & 7);
    const bf16* ga = A  + (size_t)(m0 + srow) * K + sblk * 8;
    const bf16* gb = Bt + (size_t)(n0 + srow) * K + sblk * 8;

    floatx4 acc[4][2];
    for (int i = 0; i < 4; ++i)
        for (int j = 0; j < 2; ++j) acc[i][j] = floatx4{0.f, 0.f, 0.f, 0.f};

    int lm7 = lm & 7;
    for (int ks = 0; ks < K; ks += 128) {
        __syncthreads();
        ASYNC16(ga + ks,                  &As[0 * 2048 + wave * 512]);
        ASYNC16(ga + ks + (size_t)16*K,   &As[1 * 2048 + wave * 512]);
        ASYNC16(ga + ks + (size_t)32*K,   &As[2 * 2048 + wave * 512]);
        ASYNC16(ga + ks + (size_t)48*K,   &As[3 * 2048 + wave * 512]);
        ASYNC16(ga + ks + (size_t)64*K,   &As[4 * 2048 + wave * 512]);
        ASYNC16(ga + ks + (size_t)80*K,   &As[5 * 2048 + wave * 512]);
        ASYNC16(ga + ks + (size_t)96*K,   &As[6 * 2048 + wave * 512]);
        ASYNC16(ga + ks + (size_t)112*K,  &As[7 * 2048 + wave * 512]);
        ASYNC16(gb + ks,                  &Bs[0 * 2048 + wave * 512]);
        ASYNC16(gb + ks + (size_t)16*K,   &Bs[1 * 2048 + wave * 512]);
        ASYNC16(gb + ks + (size_t)32*K,   &Bs[2 * 2048 + wave * 512]);
        ASYNC16(gb + ks + (size_t)48*K,   &Bs[3 * 2048 + wave * 512]);
        __syncthreads();
        for (int kh = 0; kh < 4; ++kh) {
            bf16x8 af[4], bfr[2];
            int blk = (kh * 4 + quad) ^ lm7;
            for (int mi = 0; mi < 4; ++mi)
                af[mi] = *(const bf16x8*)&As[(wr * 64 + mi * 16 + lm) * 128 + blk * 8];
            for (int ni = 0; ni < 2; ++ni)
                bfr[ni] = *(const bf16x8*)&Bs[(wc * 32 + ni * 16 + lm) * 128 + blk * 8];
            for (int mi = 0; mi < 4; ++mi)
                for (int ni = 0; ni < 2; ++ni)
                    acc[mi][ni] = __builtin_amdgcn_mfma_f32_16x16x32_bf16(
                        af[mi], bfr[ni], acc[mi][ni], 0, 0, 0);
        }
    }
    for (int mi = 0; mi < 4; ++mi)
        for (int ni = 0; ni < 2; ++ni)
            for (int r = 0; r < 4; ++r) {
                size_t row = (size_t)(m0 + wr * 64 + mi * 16 + quad * 4 + r);
                Cf[row * N + n0 + wc * 32 + ni * 16 + lm] = acc[mi][ni][r];
            }
}

// ---------- flash attention: 8-wave WG, paired q-blocks sharing K/V ----------
// Waves 0-3 process block p, waves 4-7 block 31-p, SHARING staging + barriers:
// chunk-rounds/CU drop 66 -> 49 while waves/CU RISE 12 -> 16 (R6's failure was
// losing waves). p = (j<32) ? j>>2 : 15-(j>>2): per-CU round sum = 49 exact
// under round-robin, longest-first. Per-wave chain identical to proven R4
// kernel; finished block-A waves stage + barrier but skip compute (uniform).
__global__ __launch_bounds__(512, 2) void attn_kernel(const bf16* __restrict__ Qr,
                                                      const bf16* __restrict__ Kr,
                                                      const bf16* __restrict__ Vt,
                                                      bf16* __restrict__ ctx) {
    __shared__ __align__(16) bf16 kv[3][8192];       // per buf: K [0,4096) | V [4096,8192)
    int t = threadIdx.x;
    int wave = t >> 6, lane = t & 63;
    int w4 = wave & 3, whichB = wave >> 2;
    int lm = lane & 15, quad = lane >> 4;
    int lm7 = lm & 7, qh = quad >> 1, ql = quad & 1;

    int bid = blockIdx.x;
    int grp = bid & 7;                 // XCD group = b*4 + kvh
    int j = bid >> 3;                  // 0..63 within group
    int b = grp >> 2, kvh = grp & 3;
    int h = kvh * 4 + (j & 3);
    int a = (j >> 2) & 7;
    int p = (j < 32) ? a : 15 - a;     // pair (p, 31-p); CU round-sum = 49
    int rounds = 32 - p;               // = nch of block B (the longer)
    int qb = whichB ? (31 - p) : p;
    int nch = qb + 1;

    const bf16* kbase = Kr + (size_t)(b * NKVH + kvh) * SS * HD;
    const bf16* vbase = Vt + (size_t)(b * NKVH + kvh) * HD * SS;
    int srow = t >> 3;                         // 0..63 (512 threads)
    int su   = (t & 7) ^ (srow & 7);           // XOR swizzle (async-LDS forbids pads)
    const bf16* gkc = kbase + (size_t)srow * HD + su * 8;
    const bf16* gvc = vbase + (size_t)srow * SS + su * 8;

// 8 waves x (1 K + 1 V) ASYNC16 = 16KB/buffer; 2 vmem ops in flight per wave
#define STAGE(buf) do {                                                        \
        ASYNC16(gkc, (buf) + wave * 512);                                      \
        ASYNC16(gvc, (buf) + 4096 + wave * 512);                               \
        gkc += 64 * HD; gvc += 64; } while (0)

    int q0w = qb * 64 + w4 * 16;

    // Q fragments, pre-scaled by SCALE (0.125 = 2^-3, exact in bf16)
    const bf16* qp = Qr + ((size_t)(b * NH + h) * SS + q0w + lm) * HD;
    bf16x8 qf0 = *(const bf16x8*)(qp + quad * 8);
    bf16x8 qf1 = *(const bf16x8*)(qp + 32 + quad * 8);
    for (int e = 0; e < 8; ++e) {
        qf0[e] = (bf16)((float)qf0[e] * SCALE);
        qf1[e] = (bf16)((float)qf1[e] * SCALE);
    }

    // hoisted LDS element-offsets (loop-invariant; ds_read gets base+imm)
    int ko0 = lm * 64 + ((quad ^ lm7) * 8);
    int ko1 = lm * 64 + (((quad + 4) ^ lm7) * 8);
    int vo0 = lm * 64 + ql * 4 + (((0 + qh) ^ lm7) * 8);
    int vo1 = lm * 64 + ql * 4 + (((2 + qh) ^ lm7) * 8);
    int vo2 = lm * 64 + ql * 4 + (((4 + qh) ^ lm7) * 8);
    int vo3 = lm * 64 + ql * 4 + (((6 + qh) ^ lm7) * 8);

    float m_prev = -1e30f, nm_prev = -1e30f, l_prev = 0.f;
    floatx4 o[4];
    for (int dt = 0; dt < 4; ++dt) o[dt] = floatx4{0.f, 0.f, 0.f, 0.f};

    bf16* cur = &kv[0][0];
    bf16* nxt = &kv[1][0];
    bf16* thd = &kv[2][0];
    STAGE(cur);                            // prologue: chunk 0 in flight

    const float L2E = 1.44269504f;
    for (int ck = 0; ck < rounds; ++ck) {
        if (ck + 1 < rounds) {
            STAGE(nxt);                    // chunk ck+1 in flight (2 newer loads)
            asm volatile("s_waitcnt vmcnt(2)" ::: "memory");   // chunk ck landed
        } else {
            asm volatile("s_waitcnt vmcnt(0)" ::: "memory");
        }
        __builtin_amdgcn_s_barrier();      // all 8 waves see buf 'cur' staged
        asm volatile("" ::: "memory");

        if (ck < nch) {                    // wave-uniform: block-A waves idle late
            const bf16* kbuf = cur;
            const bf16* vbuf = cur + 4096;
            const bf16* kp0 = kbuf + ko0;
            const bf16* kp1 = kbuf + ko1;

            __builtin_amdgcn_s_setprio(1);
            // S^T = K·Q^T (rows = keys, cols = queries; lane lm = its query)
            floatx4 st[4];
            for (int tt = 0; tt < 4; ++tt) {
                bf16x8 k0 = *(const bf16x8*)(kp0 + tt * 1024);
                bf16x8 k1 = *(const bf16x8*)(kp1 + tt * 1024);
                floatx4 s = {0.f, 0.f, 0.f, 0.f};
                s = __builtin_amdgcn_mfma_f32_16x16x32_bf16(k0, qf0, s, 0, 0, 0);
                s = __builtin_amdgcn_mfma_f32_16x16x32_bf16(k1, qf1, s, 0, 0, 0);
                st[tt] = s;
            }
            if (ck == nch - 1) {               // causal mask (diag chunk only)
                int kb = ck * 64;
                for (int tt = 0; tt < 4; ++tt)
                    for (int r2 = 0; r2 < 4; ++r2)
                        if (kb + tt * 16 + quad * 4 + r2 > q0w + lm)
                            st[tt][r2] = -1e30f;
            }
            // v_max3 tree over 16 regs + 2 cross-quad shuffles
            float a0 = max3f(st[0][0], st[0][1], st[0][2]);
            float a1 = max3f(st[0][3], st[1][0], st[1][1]);
            float a2 = max3f(st[1][2], st[1][3], st[2][0]);
            float a3 = max3f(st[2][1], st[2][2], st[2][3]);
            float a4 = max3f(st[3][0], st[3][1], st[3][2]);
            float mx = max3f(max3f(a0, a1, a2), max3f(a3, a4, st[3][3]), -1e30f);
            mx = fmaxf(mx, __shfl_xor(mx, 16));
            mx = fmaxf(mx, __shfl_xor(mx, 32));
            float m_new = fmaxf(m_prev, mx);
            float nm = m_new * L2E;
            if (__any(mx > m_prev)) {          // exact skip when max unchanged
                float alpha = exp2_hw(nm_prev - nm);
                l_prev *= alpha;
                for (int r2 = 0; r2 < 4; ++r2) {
                    float aa = __shfl(alpha, quad * 4 + r2);
                    for (int dt = 0; dt < 4; ++dt) o[dt][r2] *= aa;
                }
            }
            m_prev = m_new; nm_prev = nm;

            bf16x4 pa[4];
            float ls = 0.f;
            for (int tt = 0; tt < 4; ++tt) {
                float p0 = exp2_hw(fmaf(st[tt][0], L2E, -nm));
                float p1 = exp2_hw(fmaf(st[tt][1], L2E, -nm));
                float p2 = exp2_hw(fmaf(st[tt][2], L2E, -nm));
                float p3 = exp2_hw(fmaf(st[tt][3], L2E, -nm));
                pa[tt] = bf16x4{(bf16)p0, (bf16)p1, (bf16)p2, (bf16)p3};
                ls += (p0 + p1) + (p2 + p3);
            }
            l_prev += ls;                      // per-lane partial; reduce at end

            // PV: K=16 MFMA, P straight from registers (no transpose).
            const bf16* vp0 = vbuf + vo0;
            const bf16* vp1 = vbuf + vo1;
            const bf16* vp2 = vbuf + vo2;
            const bf16* vp3 = vbuf + vo3;
            for (int dt = 0; dt < 4; ++dt) {
                o[dt] = mfma16(pa[0], *(const bf16x4*)(vp0 + dt * 1024), o[dt]);
                o[dt] = mfma16(pa[1], *(const bf16x4*)(vp1 + dt * 1024), o[dt]);
                o[dt] = mfma16(pa[2], *(const bf16x4*)(vp2 + dt * 1024), o[dt]);
                o[dt] = mfma16(pa[3], *(const bf16x4*)(vp3 + dt * 1024), o[dt]);
            }
            __builtin_amdgcn_s_setprio(0);
        }

        bf16* tmp = cur; cur = nxt; nxt = thd; thd = tmp;   // rotate buffers
    }
    // deferred cross-quad l reduction
    float lt = l_prev;
    lt += __shfl_xor(lt, 16);
    lt += __shfl_xor(lt, 32);
    float linv = 1.f / lt;
    for (int r2 = 0; r2 < 4; ++r2) {
        float inv = __shfl(linv, quad * 4 + r2);
        int qi = q0w + quad * 4 + r2;
        for (int dt = 0; dt < 4; ++dt)
            ctx[((size_t)b * SS + qi) * DD + h * HD + dt * 16 + lm] =
                (bf16)(o[dt][r2] * inv);
    }
#undef STAGE
}

// ---------- host ----------
extern "C" void kernel_launch(void* const* d_in, const int* in_sizes, int n_in,
                              void* d_out, int out_size, void* d_ws, size_t ws_size,
                              hipStream_t stream) {
    const float* hs   = (const float*)d_in[0];
    const float* cosb = (const float*)d_in[1];
    const float* sinb = (const float*)d_in[2];
    const float* Wq = (const float*)d_in[4];
    const float* Wk = (const float*)d_in[5];
    const float* Wv = (const float*)d_in[6];
    const float* Wo = (const float*)d_in[7];
    float* out = (float*)d_out;

    char* ws = (char*)d_ws;
    size_t off = 0;
    auto alloc = [&](size_t bytes) {
        char* p = ws + off;
        off += (bytes + 255) & ~(size_t)255;
        return p;
    };
    const size_t MT = (size_t)BB * SS;                    // 4096 tokens
    bf16* hsb     = (bf16*)alloc(MT * DD * 2);
    bf16* WqkvT   = (bf16*)alloc((size_t)QKVN * DD * 2);
    bf16* WoT     = (bf16*)alloc((size_t)DD * DD * 2);
    bf16* Qr      = (bf16*)alloc(MT * DD * 2);
    bf16* Kr      = (bf16*)alloc(MT * 256 * 2);
    bf16* Vt      = (bf16*)alloc(MT * 256 * 2);
    bf16* ctx     = (bf16*)alloc(MT * DD * 2);

    // 1. prep: tiled weight transposes + hs cast
    prep_kernel<<<384 + 256 + 4096, 256, 0, stream>>>(hs, Wq, Wk, Wv, Wo,
                                                      hsb, WqkvT, WoT);
    // 2. fused QKV projection + RoPE + V scatter (128x64 tile, 768 WGs = 3/CU)
    gemm_qkv<<<dim3(MT / 128, QKVN / 64), 256, 0, stream>>>(hsb, WqkvT, cosb, sinb,
                                                            Qr, Kr, Vt);
    // 3. attention (512 WGs x 512 thr = 2/CU, 16 waves/CU; paired q-blocks)
    attn_kernel<<<512, 512, 0, stream>>>(Qr, Kr, Vt, ctx);
    // 4. output projection (128x64 tile, 512 WGs = 2/CU, fp32 out, BK=128)
    gemm_out<<<dim3(MT / 128, DD / 64), 256, 0, stream>>>(ctx, WoT, out,
                                                          (int)MT, DD, DD);

    (void)in_sizes; (void)n_in; (void)out_size; (void)ws_size;
}

// Round 11
// 162.556 us; speedup vs baseline: 1.0364x; 1.0364x over previous
//
#include <hip/hip_runtime.h>

#define BB 2
#define SS 2048
#define DD 1024
#define NH 16
#define NKVH 4
#define HD 64
#define QKVN 1536          // fused Wqkv output columns: 1024 q | 256 k | 256 v
#define SCALE 0.125f       // 64^-0.5, exact power of 2 -> folded into Q frags

typedef __bf16 bf16;
typedef __bf16 bf16x4 __attribute__((ext_vector_type(4)));
typedef __bf16 bf16x8 __attribute__((ext_vector_type(8)));
typedef float floatx4 __attribute__((ext_vector_type(4)));
typedef short short4s __attribute__((ext_vector_type(4)));

#define ASYNC16(gp, lp) __builtin_amdgcn_global_load_lds(                      \
    (const __attribute__((address_space(1))) unsigned int*)(gp),               \
    (__attribute__((address_space(3))) unsigned int*)(lp), 16, 0, 0)

// hardware 2^x (v_exp_f32 is natively base-2)
static __device__ __forceinline__ float exp2_hw(float x) {
#if __has_builtin(__builtin_amdgcn_exp2f)
    return __builtin_amdgcn_exp2f(x);
#else
    float r; asm("v_exp_f32 %0, %1" : "=v"(r) : "v"(x)); return r;
#endif
}

static __device__ __forceinline__ float max3f(float a, float b, float c) {
    return fmaxf(fmaxf(a, b), c);
}

// K=16 bf16 MFMA: A-frag layout (row=lane&15, k=quad*4+e) == our S^T C-layout,
// so P feeds PV with ZERO transpose (no p_lds roundtrip).
static __device__ __forceinline__ floatx4 mfma16(bf16x4 a, bf16x4 b, floatx4 c) {
#if __has_builtin(__builtin_amdgcn_mfma_f32_16x16x16bf16_1k)
    return __builtin_amdgcn_mfma_f32_16x16x16bf16_1k(
        __builtin_bit_cast(short4s, a), __builtin_bit_cast(short4s, b), c, 0, 0, 0);
#else
    asm("v_mfma_f32_16x16x16_bf16 %0, %1, %2, %0" : "+v"(c) : "v"(a), "v"(b));
    return c;
#endif
}

// ---------- prep: LDS-tiled weight transposes + hs cast ----------
__global__ __launch_bounds__(256) void prep_kernel(const float* __restrict__ hs,
                                                   const float* __restrict__ Wq,
                                                   const float* __restrict__ Wk,
                                                   const float* __restrict__ Wv,
                                                   const float* __restrict__ Wo,
                                                   bf16* __restrict__ hsb,
                                                   bf16* __restrict__ WqkvT,
                                                   bf16* __restrict__ WoT) {
    __shared__ bf16 tl[64 * 66];
    int bidx = blockIdx.x, t = threadIdx.x;
    const int NT_QKV = 16 * 24;    // K/64 x QKVN/64
    const int NT_WO  = 16 * 16;
    if (bidx < NT_QKV + NT_WO) {
        int k0, n0, stride;
        const float* src;
        bf16* dst;
        if (bidx < NT_QKV) {
            int tk = bidx / 24, tn = bidx - tk * 24;
            k0 = tk * 64; n0 = tn * 64;
            if (n0 < 1024)      { src = Wq + n0;          stride = 1024; }
            else if (n0 < 1280) { src = Wk + (n0 - 1024); stride = 256;  }
            else                { src = Wv + (n0 - 1280); stride = 256;  }
            dst = WqkvT + (size_t)n0 * DD + k0;
        } else {
            int j = bidx - NT_QKV;
            int tk = j >> 4, tn = j & 15;
            k0 = tk * 64; n0 = tn * 64;
            src = Wo + n0; stride = 1024;
            dst = WoT + (size_t)n0 * DD + k0;
        }
        int c = t & 63, r0 = (t >> 6) * 16;
        for (int j = 0; j < 16; ++j)
            tl[c * 66 + r0 + j] = (bf16)src[(size_t)(k0 + r0 + j) * stride + c];
        __syncthreads();
        for (int j = 0; j < 16; ++j)
            dst[(size_t)(r0 + j) * DD + c] = tl[(r0 + j) * 66 + c];
    } else {
        int i = (bidx - (NT_QKV + NT_WO)) * 256 + t;   // n4 = 1048576 exactly
        float4 v = ((const float4*)hs)[i];
        ((bf16x4*)hsb)[i] = bf16x4{(bf16)v.x, (bf16)v.y, (bf16)v.z, (bf16)v.w};
    }
}

// ---------- QKV GEMM (128x64 tile, BK=128, swizzled LDS) + RoPE epilogue -----
// R7 measured-best config (163.9 us total). Grid 768 = 3/CU.
__global__ __launch_bounds__(256) void gemm_qkv(const bf16* __restrict__ A,
                                                const bf16* __restrict__ Bt,
                                                const float* __restrict__ cosb,
                                                const float* __restrict__ sinb,
                                                bf16* __restrict__ Qr,
                                                bf16* __restrict__ Kr,
                                                bf16* __restrict__ Vt) {
    __shared__ __align__(16) bf16 As[128 * 128];   // 32 KB
    __shared__ __align__(16) bf16 Bs[64 * 128];    // 16 KB
    int t = threadIdx.x;
    int wave = t >> 6, lane = t & 63;
    int lm = lane & 15, quad = lane >> 4;
    int m0 = blockIdx.x * 128, n0 = blockIdx.y * 64;
    int wr = wave >> 1, wc = wave & 1;      // 64m x 32n per wave
    const int K = DD;

    int srow = t >> 4;                      // 0..15
    int sblk = (t & 15) ^ (srow & 7);       // pre-swizzled 8-elem col block
    const bf16* ga = A  + (size_t)(m0 + srow) * K + sblk * 8;
    const bf16* gb = Bt + (size_t)(n0 + srow) * K + sblk * 8;

    floatx4 acc[4][2];
    for (int i = 0; i < 4; ++i)
        for (int j = 0; j < 2; ++j) acc[i][j] = floatx4{0.f, 0.f, 0.f, 0.f};

    int lm7 = lm & 7;
    for (int ks = 0; ks < K; ks += 128) {
        __syncthreads();
        ASYNC16(ga + ks,                  &As[0 * 2048 + wave * 512]);
        ASYNC16(ga + ks + (size_t)16*K,   &As[1 * 2048 + wave * 512]);
        ASYNC16(ga + ks + (size_t)32*K,   &As[2 * 2048 + wave * 512]);
        ASYNC16(ga + ks + (size_t)48*K,   &As[3 * 2048 + wave * 512]);
        ASYNC16(ga + ks + (size_t)64*K,   &As[4 * 2048 + wave * 512]);
        ASYNC16(ga + ks + (size_t)80*K,   &As[5 * 2048 + wave * 512]);
        ASYNC16(ga + ks + (size_t)96*K,   &As[6 * 2048 + wave * 512]);
        ASYNC16(ga + ks + (size_t)112*K,  &As[7 * 2048 + wave * 512]);
        ASYNC16(gb + ks,                  &Bs[0 * 2048 + wave * 512]);
        ASYNC16(gb + ks + (size_t)16*K,   &Bs[1 * 2048 + wave * 512]);
        ASYNC16(gb + ks + (size_t)32*K,   &Bs[2 * 2048 + wave * 512]);
        ASYNC16(gb + ks + (size_t)48*K,   &Bs[3 * 2048 + wave * 512]);
        __syncthreads();
        for (int kh = 0; kh < 4; ++kh) {
            bf16x8 af[4], bfr[2];
            int blk = (kh * 4 + quad) ^ lm7;
            for (int mi = 0; mi < 4; ++mi)
                af[mi] = *(const bf16x8*)&As[(wr * 64 + mi * 16 + lm) * 128 + blk * 8];
            for (int ni = 0; ni < 2; ++ni)
                bfr[ni] = *(const bf16x8*)&Bs[(wc * 32 + ni * 16 + lm) * 128 + blk * 8];
            for (int mi = 0; mi < 4; ++mi)
                for (int ni = 0; ni < 2; ++ni)
                    acc[mi][ni] = __builtin_amdgcn_mfma_f32_16x16x32_bf16(
                        af[mi], bfr[ni], acc[mi][ni], 0, 0, 0);
        }
    }
    bool odd = lm & 1;
    for (int mi = 0; mi < 4; ++mi)
        for (int ni = 0; ni < 2; ++ni) {
            int c0 = n0 + wc * 32 + ni * 16;
            int row0 = m0 + wr * 64 + mi * 16 + quad * 4;
            floatx4 a = acc[mi][ni];
            int d = (c0 & 63) + lm;
            if (c0 < 1280) {               // Q or K: apply RoPE
                int ii = d >> 1;
                for (int r = 0; r < 4; ++r) {
                    int row = row0 + r;
                    float self = a[r];
                    float part = __shfl_xor(self, 1);
                    float cc = cosb[(size_t)row * 32 + ii];
                    float sn = sinb[(size_t)row * 32 + ii];
                    float outv = odd ? fmaf(part, sn, self * cc)
                                     : fmaf(self, cc, -part * sn);
                    int s = row & (SS - 1), b = row >> 11;
                    if (c0 < 1024) {
                        int h = c0 >> 6;
                        Qr[((size_t)(b * NH + h) * SS + s) * HD + d] = (bf16)outv;
                    } else {
                        int kvh = (c0 - 1024) >> 6;
                        Kr[((size_t)(b * NKVH + kvh) * SS + s) * HD + d] = (bf16)outv;
                    }
                }
            } else {                       // V: transposed packed store
                int kvh = (c0 - 1280) >> 6;
                bf16x4 pk = {(bf16)a[0], (bf16)a[1], (bf16)a[2], (bf16)a[3]};
                int s0 = row0 & (SS - 1), b = row0 >> 11;
                *(bf16x4*)&Vt[((size_t)(b * NKVH + kvh) * HD + d) * SS + s0] = pk;
            }
        }
}

// ---------- O-projection GEMM (128x64 tile, BK=128, swizzled, fp32 out) -----
__global__ __launch_bounds__(256) void gemm_out(const bf16* __restrict__ A,
                                                const bf16* __restrict__ Bt,
                                                float* __restrict__ Cf,
                                                int M, int N, int K) {
    __shared__ __align__(16) bf16 As[128 * 128];
    __shared__ __align__(16) bf16 Bs[64 * 128];
    int t = threadIdx.x;
    int wave = t >> 6, lane = t & 63;
    int lm = lane & 15, quad = lane >> 4;
    int m0 = blockIdx.x * 128, n0 = blockIdx.y * 64;
    int wr = wave >> 1, wc = wave & 1;

    int srow = t >> 4;
    int sblk = (t & 15) ^ (srow & 7);
    const bf16* ga = A  + (size_t)(m0 + srow) * K + sblk * 8;
    const bf16* gb = Bt + (size_t)(n0 + srow) * K + sblk * 8;

    floatx4 acc[4][2];
    for (int i = 0; i < 4; ++i)
        for (int j = 0; j < 2; ++j) acc[i][j] = floatx4{0.f, 0.f, 0.f, 0.f};

    int lm7 = lm & 7;
    for (int ks = 0; ks < K; ks += 128) {
        __syncthreads();
        ASYNC16(ga + ks,                  &As[0 * 2048 + wave * 512]);
        ASYNC16(ga + ks + (size_t)16*K,   &As[1 * 2048 + wave * 512]);
        ASYNC16(ga + ks + (size_t)32*K,   &As[2 * 2048 + wave * 512]);
        ASYNC16(ga + ks + (size_t)48*K,   &As[3 * 2048 + wave * 512]);
        ASYNC16(ga + ks + (size_t)64*K,   &As[4 * 2048 + wave * 512]);
        ASYNC16(ga + ks + (size_t)80*K,   &As[5 * 2048 + wave * 512]);
        ASYNC16(ga + ks + (size_t)96*K,   &As[6 * 2048 + wave * 512]);
        ASYNC16(ga + ks + (size_t)112*K,  &As[7 * 2048 + wave * 512]);
        ASYNC16(gb + ks,                  &Bs[0 * 2048 + wave * 512]);
        ASYNC16(gb + ks + (size_t)16*K,   &Bs[1 * 2048 + wave * 512]);
        ASYNC16(gb + ks + (size_t)32*K,   &Bs[2 * 2048 + wave * 512]);
        ASYNC16(gb + ks + (size_t)48*K,   &Bs[3 * 2048 + wave * 512]);
        __syncthreads();
        for (int kh = 0; kh < 4; ++kh) {
            bf16x8 af[4], bfr[2];
            int blk = (kh * 4 + quad) ^ lm7;
            for (int mi = 0; mi < 4; ++mi)
                af[mi] = *(const bf16x8*)&As[(wr * 64 + mi * 16 + lm) * 128 + blk * 8];
            for (int ni = 0; ni < 2; ++ni)
                bfr[ni] = *(const bf16x8*)&Bs[(wc * 32 + ni * 16 + lm) * 128 + blk * 8];
            for (int mi = 0; mi < 4; ++mi)
                for (int ni = 0; ni < 2; ++ni)
                    acc[mi][ni] = __builtin_amdgcn_mfma_f32_16x16x32_bf16(
                        af[mi], bfr[ni], acc[mi][ni], 0, 0, 0);
        }
    }
    for (int mi = 0; mi < 4; ++mi)
        for (int ni = 0; ni < 2; ++ni)
            for (int r = 0; r < 4; ++r) {
                size_t row = (size_t)(m0 + wr * 64 + mi * 16 + quad * 4 + r);
                Cf[row * N + n0 + wc * 32 + ni * 16 + lm] = acc[mi][ni][r];
            }
}

// ---------- flash attention: triple-buffered counted-vmcnt pipeline ----------
// R4/R7 kernel + T13 defer-max (THR=8): skip the O-rescale unless the chunk
// max grew by >8; old running max kept, so P <= e^8 (bf16-safe, HK-validated).
// Removes VALU work (max bookkeeping + 4 shfl + 16 mul + exp) from the serial
// softmax chain on most chunks. Balanced longest-first mapping: per-CU chunk
// sum = 66 for all CUs under round-robin.
__global__ __launch_bounds__(256, 3) void attn_kernel(const bf16* __restrict__ Qr,
                                                      const bf16* __restrict__ Kr,
                                                      const bf16* __restrict__ Vt,
                                                      bf16* __restrict__ ctx) {
    __shared__ __align__(16) bf16 kv[3][8192];       // per buf: K [0,4096) | V [4096,8192)
    int t = threadIdx.x;
    int wave = t >> 6, lane = t & 63;
    int lm = lane & 15, quad = lane >> 4;
    int lm7 = lm & 7, qh = quad >> 1, ql = quad & 1;

    int bid = blockIdx.x;
    int grp = bid & 7;                 // XCD group = b*4 + kvh
    int j = bid >> 3;                  // 0..127 within group
    int b = grp >> 2, kvh = grp & 3;
    int h = kvh * 4 + (j & 3);
    int r = j >> 5, g = (j >> 2) & 7;
    int qb;
    switch (r) {
        case 0:  qb = 31 - g; break;
        case 1:  qb = 16 + g; break;
        case 2:  qb = 15 - g; break;
        default: qb = g;      break;
    }

    const bf16* kbase = Kr + (size_t)(b * NKVH + kvh) * SS * HD;
    const bf16* vbase = Vt + (size_t)(b * NKVH + kvh) * HD * SS;
    int srow = t >> 3;                         // 0..31
    int su   = (t & 7) ^ (srow & 7);           // XOR swizzle (async-LDS forbids pads)
    const bf16* gkc = kbase + (size_t)srow * HD + su * 8;
    const bf16* gvc = vbase + (size_t)srow * SS + su * 8;

#define STAGE(buf) do { bf16* l = (buf) + wave * 512;                          \
        ASYNC16(gkc,                  l);                                      \
        ASYNC16(gkc + 32 * HD,        l + 2048);                               \
        ASYNC16(gvc,                  l + 4096);                               \
        ASYNC16(gvc + (size_t)32 * SS, l + 6144);                              \
        gkc += 64 * HD; gvc += 64; } while (0)

    int q0w = qb * 64 + wave * 16;

    // Q fragments, pre-scaled by SCALE (0.125 = 2^-3, exact in bf16)
    const bf16* qp = Qr + ((size_t)(b * NH + h) * SS + q0w + lm) * HD;
    bf16x8 qf0 = *(const bf16x8*)(qp + quad * 8);
    bf16x8 qf1 = *(const bf16x8*)(qp + 32 + quad * 8);
    for (int e = 0; e < 8; ++e) {
        qf0[e] = (bf16)((float)qf0[e] * SCALE);
        qf1[e] = (bf16)((float)qf1[e] * SCALE);
    }

    // hoisted LDS element-offsets (loop-invariant; ds_read gets base+imm)
    int ko0 = lm * 64 + ((quad ^ lm7) * 8);
    int ko1 = lm * 64 + (((quad + 4) ^ lm7) * 8);
    int vo0 = lm * 64 + ql * 4 + (((0 + qh) ^ lm7) * 8);
    int vo1 = lm * 64 + ql * 4 + (((2 + qh) ^ lm7) * 8);
    int vo2 = lm * 64 + ql * 4 + (((4 + qh) ^ lm7) * 8);
    int vo3 = lm * 64 + ql * 4 + (((6 + qh) ^ lm7) * 8);

    float m_prev = -1e30f, nm_prev = -1e30f, l_prev = 0.f;
    floatx4 o[4];
    for (int dt = 0; dt < 4; ++dt) o[dt] = floatx4{0.f, 0.f, 0.f, 0.f};

    int nch = qb + 1;
    bf16* cur = &kv[0][0];
    bf16* nxt = &kv[1][0];
    bf16* thd = &kv[2][0];
    STAGE(cur);                            // prologue: chunk 0 in flight

    const float L2E = 1.44269504f;
    for (int ck = 0; ck < nch; ++ck) {
        if (ck + 1 < nch) {
            STAGE(nxt);                    // chunk ck+1 in flight (4 newer loads)
            asm volatile("s_waitcnt vmcnt(4)" ::: "memory");   // chunk ck landed
        } else {
            asm volatile("s_waitcnt vmcnt(0)" ::: "memory");
        }
        __builtin_amdgcn_s_barrier();      // all waves see buf 'cur' staged
        asm volatile("" ::: "memory");

        const bf16* kbuf = cur;
        const bf16* vbuf = cur + 4096;
        const bf16* kp0 = kbuf + ko0;
        const bf16* kp1 = kbuf + ko1;

        __builtin_amdgcn_s_setprio(1);
        // S^T = K·Q^T (rows = keys, cols = queries; lane lm = its query)
        floatx4 st[4];
        for (int tt = 0; tt < 4; ++tt) {
            bf16x8 k0 = *(const bf16x8*)(kp0 + tt * 1024);
            bf16x8 k1 = *(const bf16x8*)(kp1 + tt * 1024);
            floatx4 s = {0.f, 0.f, 0.f, 0.f};
            s = __builtin_amdgcn_mfma_f32_16x16x32_bf16(k0, qf0, s, 0, 0, 0);
            s = __builtin_amdgcn_mfma_f32_16x16x32_bf16(k1, qf1, s, 0, 0, 0);
            st[tt] = s;
        }
        if (ck == nch - 1) {                   // causal mask (diag chunk only)
            int kb = ck * 64;
            for (int tt = 0; tt < 4; ++tt)
                for (int r2 = 0; r2 < 4; ++r2)
                    if (kb + tt * 16 + quad * 4 + r2 > q0w + lm) st[tt][r2] = -1e30f;
        }
        // v_max3 tree over 16 regs + 2 cross-quad shuffles
        float a0 = max3f(st[0][0], st[0][1], st[0][2]);
        float a1 = max3f(st[0][3], st[1][0], st[1][1]);
        float a2 = max3f(st[1][2], st[1][3], st[2][0]);
        float a3 = max3f(st[2][1], st[2][2], st[2][3]);
        float a4 = max3f(st[3][0], st[3][1], st[3][2]);
        float mx = fmaxf(max3f(a0, a1, a2), max3f(a3, a4, st[3][3]));
        mx = fmaxf(mx, __shfl_xor(mx, 16));
        mx = fmaxf(mx, __shfl_xor(mx, 32));
        // T13 defer-max: rescale only when max grew by >8 (P bounded by e^8)
        if (__any(mx > m_prev + 8.0f)) {
            float m_new = fmaxf(m_prev, mx);
            float nm = m_new * L2E;
            float alpha = exp2_hw(nm_prev - nm);
            l_prev *= alpha;
            for (int r2 = 0; r2 < 4; ++r2) {
                float a = __shfl(alpha, quad * 4 + r2);
                for (int dt = 0; dt < 4; ++dt) o[dt][r2] *= a;
            }
            m_prev = m_new; nm_prev = nm;
        }

        bf16x4 pa[4];
        float ls = 0.f;
        for (int tt = 0; tt < 4; ++tt) {
            float p0 = exp2_hw(fmaf(st[tt][0], L2E, -nm_prev));
            float p1 = exp2_hw(fmaf(st[tt][1], L2E, -nm_prev));
            float p2 = exp2_hw(fmaf(st[tt][2], L2E, -nm_prev));
            float p3 = exp2_hw(fmaf(st[tt][3], L2E, -nm_prev));
            pa[tt] = bf16x4{(bf16)p0, (bf16)p1, (bf16)p2, (bf16)p3};
            ls += (p0 + p1) + (p2 + p3);
        }
        l_prev += ls;                          // per-lane partial; reduce at end

        // PV: K=16 MFMA, P straight from registers (no transpose).
        const bf16* vp0 = vbuf + vo0;
        const bf16* vp1 = vbuf + vo1;
        const bf16* vp2 = vbuf + vo2;
        const bf16* vp3 = vbuf + vo3;
        for (int dt = 0; dt < 4; ++dt) {
            o[dt] = mfma16(pa[0], *(const bf16x4*)(vp0 + dt * 1024), o[dt]);
            o[dt] = mfma16(pa[1], *(const bf16x4*)(vp1 + dt * 1024), o[dt]);
            o[dt] = mfma16(pa[2], *(const bf16x4*)(vp2 + dt * 1024), o[dt]);
            o[dt] = mfma16(pa[3], *(const bf16x4*)(vp3 + dt * 1024), o[dt]);
        }
        __builtin_amdgcn_s_setprio(0);

        bf16* tmp = cur; cur = nxt; nxt = thd; thd = tmp;   // rotate buffers
    }
    // deferred cross-quad l reduction
    float lt = l_prev;
    lt += __shfl_xor(lt, 16);
    lt += __shfl_xor(lt, 32);
    float linv = 1.f / lt;
    for (int r2 = 0; r2 < 4; ++r2) {
        float inv = __shfl(linv, quad * 4 + r2);
        int qi = q0w + quad * 4 + r2;
        for (int dt = 0; dt < 4; ++dt)
            ctx[((size_t)b * SS + qi) * DD + h * HD + dt * 16 + lm] =
                (bf16)(o[dt][r2] * inv);
    }
#undef STAGE
}

// ---------- host ----------
extern "C" void kernel_launch(void* const* d_in, const int* in_sizes, int n_in,
                              void* d_out, int out_size, void* d_ws, size_t ws_size,
                              hipStream_t stream) {
    const float* hs   = (const float*)d_in[0];
    const float* cosb = (const float*)d_in[1];
    const float* sinb = (const float*)d_in[2];
    const float* Wq = (const float*)d_in[4];
    const float* Wk = (const float*)d_in[5];
    const float* Wv = (const float*)d_in[6];
    const float* Wo = (const float*)d_in[7];
    float* out = (float*)d_out;

    char* ws = (char*)d_ws;
    size_t off = 0;
    auto alloc = [&](size_t bytes) {
        char* p = ws + off;
        off += (bytes + 255) & ~(size_t)255;
        return p;
    };
    const size_t MT = (size_t)BB * SS;                    // 4096 tokens
    bf16* hsb     = (bf16*)alloc(MT * DD * 2);
    bf16* WqkvT   = (bf16*)alloc((size_t)QKVN * DD * 2);
    bf16* WoT     = (bf16*)alloc((size_t)DD * DD * 2);
    bf16* Qr      = (bf16*)alloc(MT * DD * 2);
    bf16* Kr      = (bf16*)alloc(MT * 256 * 2);
    bf16* Vt      = (bf16*)alloc(MT * 256 * 2);
    bf16* ctx     = (bf16*)alloc(MT * DD * 2);

    // 1. prep: tiled weight transposes + hs cast
    prep_kernel<<<384 + 256 + 4096, 256, 0, stream>>>(hs, Wq, Wk, Wv, Wo,
                                                      hsb, WqkvT, WoT);
    // 2. fused QKV projection + RoPE + V scatter (128x64 tile, 768 WGs = 3/CU)
    gemm_qkv<<<dim3(MT / 128, QKVN / 64), 256, 0, stream>>>(hsb, WqkvT, cosb, sinb,
                                                            Qr, Kr, Vt);
    // 3. attention (1024 WGs, 3/CU; balanced longest-first mapping)
    attn_kernel<<<1024, 256, 0, stream>>>(Qr, Kr, Vt, ctx);
    // 4. output projection (128x64 tile, 512 WGs = 2/CU, fp32 out, BK=128)
    gemm_out<<<dim3(MT / 128, DD / 64), 256, 0, stream>>>(ctx, WoT, out,
                                                          (int)MT, DD, DD);

    (void)in_sizes; (void)n_in; (void)out_size; (void)ws_size;
}